// Round 2
// baseline (147.787 us; speedup 1.0000x reference)
//
#include <hip/hip_runtime.h>

#define HH 160
#define WW 160
#define DD 160
#define BB 4
#define NPB (HH * WW * DD / 4)   // 1,024,000 float4 per batch
#define K1B 256                   // min-pass blocks per batch

typedef float vfloat4 __attribute__((ext_vector_type(4)));

// ---- kernel 1: per-batch block-partial min (NO atomics) + affine constants ----
// grid (256, BB) x 256. Each thread reads 16 float4 (4 rounds, MLP=4),
// stride 65536 float4. Block partial min -> partial[b*256 + bx].
// Block (0, y=0) threads 0..3 also compute fp64 affine constants:
//   ix = R00*x + R01*y + R02*z + 79.5*(t0 - R00 - R01 - R02 + 1)
// (exact fold of linspace + cx scaling, since 79.5*(2/159) == 1).
__global__ __launch_bounds__(256) void min_cst_kernel(const float4* __restrict__ img4,
                                                      const float* __restrict__ transfos,
                                                      float* __restrict__ partial,
                                                      double* __restrict__ cst) {
    const int b = blockIdx.y;
    const size_t base = (size_t)b * NPB;
    const int t0 = blockIdx.x * 256 + threadIdx.x;   // < 65536
    const int S = K1B * 256;                          // 65536

    float m = 3.4e38f;
    #pragma unroll
    for (int r = 0; r < 4; r++) {
        const int i0 = t0 + 4 * r * S;
        float4 v0 = img4[base + i0];
        float4 v1 = img4[base + i0 + S];
        float4 v2 = img4[base + i0 + 2 * S];
        float4 v3 = make_float4(3.4e38f, 3.4e38f, 3.4e38f, 3.4e38f);
        if (i0 + 3 * S < NPB) v3 = img4[base + i0 + 3 * S];   // only r==3 can fail
        m = fminf(m, fminf(fminf(v0.x, v0.y), fminf(v0.z, v0.w)));
        m = fminf(m, fminf(fminf(v1.x, v1.y), fminf(v1.z, v1.w)));
        m = fminf(m, fminf(fminf(v2.x, v2.y), fminf(v2.z, v2.w)));
        m = fminf(m, fminf(fminf(v3.x, v3.y), fminf(v3.z, v3.w)));
    }

    #pragma unroll
    for (int o = 32; o >= 1; o >>= 1) m = fminf(m, __shfl_down(m, o));
    __shared__ float s[4];
    const int lane = threadIdx.x & 63, wid = threadIdx.x >> 6;
    if (lane == 0) s[wid] = m;
    __syncthreads();
    if (threadIdx.x == 0) {
        partial[b * K1B + blockIdx.x] =
            fminf(fminf(s[0], s[1]), fminf(s[2], s[3]));
    }

    // affine constants (fp64), once per batch, by block (0,0) threads 0..3
    if (blockIdx.x == 0 && blockIdx.y == 0 && threadIdx.x < BB) {
        const int bb = threadIdx.x;
        const float* q = transfos + bb * 7;
        double x = q[0], y = q[1], z = q[2], w = q[3];
        double tx = 2.0 * x, ty = 2.0 * y, tz = 2.0 * z;
        double twx = tx * w, twy = ty * w, twz = tz * w;
        double txx = tx * x, txy = ty * x, txz = tz * x;
        double tyy = ty * y, tyz = tz * y, tzz = tz * z;
        double R[3][3] = {
            {1.0 - (tyy + tzz), txy - twz,         txz + twy},
            {txy + twz,         1.0 - (txx + tzz), tyz - twx},
            {txz - twy,         tyz + twx,         1.0 - (txx + tyy)}
        };
        double t[3] = {(double)q[4], (double)q[5], (double)q[6]};
        for (int r = 0; r < 3; r++) {
            cst[bb * 12 + r * 4 + 0] = R[r][0];
            cst[bb * 12 + r * 4 + 1] = R[r][1];
            cst[bb * 12 + r * 4 + 2] = R[r][2];
            cst[bb * 12 + r * 4 + 3] = 79.5 * (t[r] - R[r][0] - R[r][1] - R[r][2] + 1.0);
        }
    }
}

// ---- kernel 1b: final per-batch min (1 block, wave w reduces batch w) ----
__global__ __launch_bounds__(256) void fin_min_kernel(const float* __restrict__ partial,
                                                      float* __restrict__ fill) {
    const int wid = threadIdx.x >> 6, lane = threadIdx.x & 63;
    const float* p = partial + wid * K1B;
    float m = fminf(fminf(p[lane], p[lane + 64]), fminf(p[lane + 128], p[lane + 192]));
    #pragma unroll
    for (int o = 32; o >= 1; o >>= 1) m = fminf(m, __shfl_down(m, o));
    if (lane == 0) fill[wid] = m;
}

// ---- kernel 2: affine map + trilinear gather, 3D-tiled, 8 z per thread ----
// Block covers an 8y x 8x x 32z output tile:
//   tz = tid&3 (8-z span each), tx = (tid>>2)&7, ty = tid>>5.
// Wave brick = 2y x 8x x 32z. No LDS, no syncthreads: fill[b] is precomputed.
// The 8 k-steps are processed as two groups of 4; each group issues all 32
// gather loads (statically-indexed register arrays) before any weight math,
// so ~32 loads are in flight per wave instead of 8.
// grid (DD/32=5, WW/8=20, (HH/8)*BB=80) x 256.
__global__ __launch_bounds__(256) void st3d_kernel(const float* __restrict__ img,
                                                   const double* __restrict__ cst,
                                                   const float* __restrict__ fill,
                                                   float* __restrict__ out) {
    const int bzc = blockIdx.z;
    const int b = bzc / 20;            // HH/8 = 20 y-tiles
    const int yt = bzc - b * 20;

    const int tz = threadIdx.x & 3;
    const int tx = (threadIdx.x >> 2) & 7;
    const int ty = threadIdx.x >> 5;

    const int x  = blockIdx.y * 8 + tx;
    const int y  = yt * 8 + ty;
    const int zq = blockIdx.x * 32 + tz * 8;

    const float fillv = fill[b];

    const double* c = cst + b * 12;
    const double c2 = c[2], c6 = c[6], c10 = c[10];
    const double dx = (double)x, dy = (double)y, dz = (double)zq;
    double ixd = fma(c[0], dx, fma(c[1], dy, fma(c2, dz, c[3])));
    double iyd = fma(c[4], dx, fma(c[5], dy, fma(c6, dz, c[7])));
    double izd = fma(c[8], dx, fma(c[9], dy, fma(c10, dz, c[11])));

    // exact per-k validity prescan (sequential stepping, identical values to
    // the main loop, so no boundary-ulp disagreement)
    bool anyv = false;
    {
        double ax = ixd, ay = iyd, az = izd;
        #pragma unroll
        for (int k = 0; k < 8; k++) {
            anyv = anyv || ((ax >= 0.0) && (ax <= 159.0) && (ay >= 0.0) &&
                            (ay <= 159.0) && (az >= 0.0) && (az <= 159.0));
            ax += c2; ay += c6; az += c10;
        }
    }

    const float* base = img + (size_t)b * (HH * WW * DD);
    vfloat4 r0, r1;

    if (__any(anyv)) {
        #pragma unroll
        for (int g = 0; g < 2; g++) {
            float v[4][8];
            float fx[4], fy[4], fz[4];
            unsigned vmask = 0;
            // phase A: addresses + loads (no uses of loaded data)
            #pragma unroll
            for (int k = 0; k < 4; k++) {
                const bool valid = (ixd >= 0.0) && (ixd <= 159.0) && (iyd >= 0.0) &&
                                   (iyd <= 159.0) && (izd >= 0.0) && (izd <= 159.0);
                if (valid) vmask |= (1u << k);
                double flx = floor(ixd), fly = floor(iyd), flz = floor(izd);
                int x0 = (int)flx, y0 = (int)fly, z0 = (int)flz;
                // clamp for address safety; no-op for valid lanes
                x0 = min(max(x0, 0), 159);
                y0 = min(max(y0, 0), 159);
                z0 = min(max(z0, 0), 159);
                fx[k] = (float)(ixd - flx);
                fy[k] = (float)(iyd - fly);
                fz[k] = (float)(izd - flz);
                int x1 = min(x0 + 1, 159), y1 = min(y0 + 1, 159), z1 = min(z0 + 1, 159);
                // img[b, h=yi, w=xi, d=zi]
                const int o00 = (y0 * WW + x0) * DD;   // (y0, x0)
                const int o01 = (y0 * WW + x1) * DD;   // (y0, x1)
                const int o10 = (y1 * WW + x0) * DD;   // (y1, x0)
                const int o11 = (y1 * WW + x1) * DD;   // (y1, x1)
                v[k][0] = base[o00 + z0];  // v000
                v[k][1] = base[o00 + z1];  // v001
                v[k][2] = base[o10 + z0];  // v010
                v[k][3] = base[o10 + z1];  // v011
                v[k][4] = base[o01 + z0];  // v100
                v[k][5] = base[o01 + z1];  // v101
                v[k][6] = base[o11 + z0];  // v110
                v[k][7] = base[o11 + z1];  // v111
                ixd += c2; iyd += c6; izd += c10;
            }
            // phase B: weights + accumulate (reference (ox,oy,oz) order)
            #pragma unroll
            for (int k = 0; k < 4; k++) {
                float wx0 = 1.0f - fx[k], wx1 = fx[k];
                float wy0 = 1.0f - fy[k], wy1 = fy[k];
                float wz0 = 1.0f - fz[k], wz1 = fz[k];
                float acc;
                acc  = ((wx0 * wy0) * wz0) * v[k][0];
                acc += ((wx0 * wy0) * wz1) * v[k][1];
                acc += ((wx0 * wy1) * wz0) * v[k][2];
                acc += ((wx0 * wy1) * wz1) * v[k][3];
                acc += ((wx1 * wy0) * wz0) * v[k][4];
                acc += ((wx1 * wy0) * wz1) * v[k][5];
                acc += ((wx1 * wy1) * wz0) * v[k][6];
                acc += ((wx1 * wy1) * wz1) * v[k][7];
                float res = ((vmask >> k) & 1u) ? acc : fillv;
                if (g == 0) r0[k] = res; else r1[k] = res;
            }
        }
    } else {
        r0[0] = fillv; r0[1] = fillv; r0[2] = fillv; r0[3] = fillv;
        r1[0] = fillv; r1[1] = fillv; r1[2] = fillv; r1[3] = fillv;
    }

    float* op = out + (size_t)((b * HH + y) * WW + x) * DD + zq;
    __builtin_nontemporal_store(r0, (vfloat4*)op);
    __builtin_nontemporal_store(r1, (vfloat4*)(op + 4));
}

extern "C" void kernel_launch(void* const* d_in, const int* in_sizes, int n_in,
                              void* d_out, int out_size, void* d_ws, size_t ws_size,
                              hipStream_t stream) {
    const float* img = (const float*)d_in[0];
    const float* transfos = (const float*)d_in[1];
    float* out = (float*)d_out;
    float* partial = (float*)d_ws;                      // 1024 floats
    double* cst = (double*)((char*)d_ws + 4096);        // 48 doubles
    float* fill = (float*)((char*)d_ws + 8192);         // 4 floats

    min_cst_kernel<<<dim3(K1B, BB), 256, 0, stream>>>((const float4*)img, transfos,
                                                      partial, cst);
    fin_min_kernel<<<dim3(1), 256, 0, stream>>>(partial, fill);
    st3d_kernel<<<dim3(DD / 32, WW / 8, (HH / 8) * BB), 256, 0, stream>>>(img, cst,
                                                                          fill, out);
}

// Round 3
// 144.251 us; speedup vs baseline: 1.0245x; 1.0245x over previous
//
#include <hip/hip_runtime.h>

#define HH 160
#define WW 160
#define DD 160
#define BB 4
#define NPB (HH * WW * DD / 4)   // 1,024,000 float4 per batch
#define K1B 256                   // min-pass blocks per batch

typedef float vfloat4 __attribute__((ext_vector_type(4)));

// ---- kernel 1: per-batch block-partial min (NO atomics) + affine constants ----
// grid (256, BB) x 256. Each thread reads 16 float4 (4 rounds, MLP=4),
// stride 65536 float4. Block partial min -> partial[b*256 + bx].
// Block (0, y=0) threads 0..3 also compute fp64 affine constants:
//   ix = R00*x + R01*y + R02*z + 79.5*(t0 - R00 - R01 - R02 + 1)
// (exact fold of linspace + cx scaling, since 79.5*(2/159) == 1).
__global__ __launch_bounds__(256) void min_cst_kernel(const float4* __restrict__ img4,
                                                      const float* __restrict__ transfos,
                                                      float* __restrict__ partial,
                                                      double* __restrict__ cst) {
    const int b = blockIdx.y;
    const size_t base = (size_t)b * NPB;
    const int t0 = blockIdx.x * 256 + threadIdx.x;   // < 65536
    const int S = K1B * 256;                          // 65536

    float m = 3.4e38f;
    #pragma unroll
    for (int r = 0; r < 4; r++) {
        const int i0 = t0 + 4 * r * S;
        float4 v0 = img4[base + i0];
        float4 v1 = img4[base + i0 + S];
        float4 v2 = img4[base + i0 + 2 * S];
        float4 v3 = make_float4(3.4e38f, 3.4e38f, 3.4e38f, 3.4e38f);
        if (i0 + 3 * S < NPB) v3 = img4[base + i0 + 3 * S];   // only r==3 can fail
        m = fminf(m, fminf(fminf(v0.x, v0.y), fminf(v0.z, v0.w)));
        m = fminf(m, fminf(fminf(v1.x, v1.y), fminf(v1.z, v1.w)));
        m = fminf(m, fminf(fminf(v2.x, v2.y), fminf(v2.z, v2.w)));
        m = fminf(m, fminf(fminf(v3.x, v3.y), fminf(v3.z, v3.w)));
    }

    #pragma unroll
    for (int o = 32; o >= 1; o >>= 1) m = fminf(m, __shfl_down(m, o));
    __shared__ float s[4];
    const int lane = threadIdx.x & 63, wid = threadIdx.x >> 6;
    if (lane == 0) s[wid] = m;
    __syncthreads();
    if (threadIdx.x == 0) {
        partial[b * K1B + blockIdx.x] =
            fminf(fminf(s[0], s[1]), fminf(s[2], s[3]));
    }

    // affine constants (fp64), once per batch, by block (0,0) threads 0..3
    if (blockIdx.x == 0 && blockIdx.y == 0 && threadIdx.x < BB) {
        const int bb = threadIdx.x;
        const float* q = transfos + bb * 7;
        double x = q[0], y = q[1], z = q[2], w = q[3];
        double tx = 2.0 * x, ty = 2.0 * y, tz = 2.0 * z;
        double twx = tx * w, twy = ty * w, twz = tz * w;
        double txx = tx * x, txy = ty * x, txz = tz * x;
        double tyy = ty * y, tyz = tz * y, tzz = tz * z;
        double R[3][3] = {
            {1.0 - (tyy + tzz), txy - twz,         txz + twy},
            {txy + twz,         1.0 - (txx + tzz), tyz - twx},
            {txz - twy,         tyz + twx,         1.0 - (txx + tyy)}
        };
        double t[3] = {(double)q[4], (double)q[5], (double)q[6]};
        for (int r = 0; r < 3; r++) {
            cst[bb * 12 + r * 4 + 0] = R[r][0];
            cst[bb * 12 + r * 4 + 1] = R[r][1];
            cst[bb * 12 + r * 4 + 2] = R[r][2];
            cst[bb * 12 + r * 4 + 3] = 79.5 * (t[r] - R[r][0] - R[r][1] - R[r][2] + 1.0);
        }
    }
}

// ---- kernel 1b: final per-batch min (1 block, wave w reduces batch w) ----
__global__ __launch_bounds__(256) void fin_min_kernel(const float* __restrict__ partial,
                                                      float* __restrict__ fill) {
    const int wid = threadIdx.x >> 6, lane = threadIdx.x & 63;
    const float* p = partial + wid * K1B;
    float m = fminf(fminf(p[lane], p[lane + 64]), fminf(p[lane + 128], p[lane + 192]));
    #pragma unroll
    for (int o = 32; o >= 1; o >>= 1) m = fminf(m, __shfl_down(m, o));
    if (lane == 0) fill[wid] = m;
}

// ---- kernel 1c: stream fill value to the ENTIRE output ----
// Pure nontemporal float4 writes; grid (512, BB) x 256, 8 float4/thread.
// Perfectly coalesced and balanced; the gather kernel then overwrites only
// the (few) tiles that can contain valid voxels.
__global__ __launch_bounds__(256) void fill_kernel(const float* __restrict__ fill,
                                                   float* __restrict__ out) {
    const int b = blockIdx.y;
    const float fv = fill[b];
    vfloat4 v; v[0] = fv; v[1] = fv; v[2] = fv; v[3] = fv;
    vfloat4* o = (vfloat4*)(out + (size_t)b * (HH * WW * DD));
    const int stride = gridDim.x * 256;
    for (int i = blockIdx.x * 256 + threadIdx.x; i < NPB; i += stride)
        __builtin_nontemporal_store(v, o + i);
}

// ---- kernel 2: affine map + trilinear gather, 3D-tiled, tile-skip ----
// Block (256 threads) covers an output tile of 8y x 8x x 16z:
//   tz = tid&3 (4 z-quads), tx = (tid>>2)&7, ty = tid>>5.
// Block-uniform conservative interval test (affine image of the tile's
// bounding box vs [-1e-3, 159.001]^3): tiles that cannot contain a valid
// voxel return immediately -- their output was already written by
// fill_kernel. Tiles that pass run the exact round-1 body (bit-identical
// valid-voxel math; invalid lanes store the identical fillv).
// grid (DD/16=10, WW/8=20, (HH/8)*BB=80) x 256.
__global__ __launch_bounds__(256) void st3d_kernel(const float* __restrict__ img,
                                                   const double* __restrict__ cst,
                                                   const float* __restrict__ fill,
                                                   float* __restrict__ out) {
    const int bzc = blockIdx.z;
    const int b = bzc / 20;            // HH/8 = 20 y-tiles
    const int yt = bzc - b * 20;

    const double* c = cst + b * 12;
    const double c2 = c[2], c6 = c[6], c10 = c[10];

    // ---- conservative tile interval test (uniform across block) ----
    {
        const double X0 = (double)(blockIdx.y * 8), X1 = X0 + 7.0;
        const double Y0 = (double)(yt * 8),         Y1 = Y0 + 7.0;
        const double Z0 = (double)(blockIdx.x * 16), Z1 = Z0 + 15.0;
        double lo, hi, t;

        lo = c[3]; hi = c[3];
        t = c[0]; if (t >= 0.0) { lo += t * X0; hi += t * X1; } else { lo += t * X1; hi += t * X0; }
        t = c[1]; if (t >= 0.0) { lo += t * Y0; hi += t * Y1; } else { lo += t * Y1; hi += t * Y0; }
        t = c2;   if (t >= 0.0) { lo += t * Z0; hi += t * Z1; } else { lo += t * Z1; hi += t * Z0; }
        if (hi < -1e-3 || lo > 159.001) return;

        lo = c[7]; hi = c[7];
        t = c[4]; if (t >= 0.0) { lo += t * X0; hi += t * X1; } else { lo += t * X1; hi += t * X0; }
        t = c[5]; if (t >= 0.0) { lo += t * Y0; hi += t * Y1; } else { lo += t * Y1; hi += t * Y0; }
        t = c6;   if (t >= 0.0) { lo += t * Z0; hi += t * Z1; } else { lo += t * Z1; hi += t * Z0; }
        if (hi < -1e-3 || lo > 159.001) return;

        lo = c[11]; hi = c[11];
        t = c[8]; if (t >= 0.0) { lo += t * X0; hi += t * X1; } else { lo += t * X1; hi += t * X0; }
        t = c[9]; if (t >= 0.0) { lo += t * Y0; hi += t * Y1; } else { lo += t * Y1; hi += t * Y0; }
        t = c10;  if (t >= 0.0) { lo += t * Z0; hi += t * Z1; } else { lo += t * Z1; hi += t * Z0; }
        if (hi < -1e-3 || lo > 159.001) return;
    }

    const int tz = threadIdx.x & 3;
    const int tx = (threadIdx.x >> 2) & 7;
    const int ty = threadIdx.x >> 5;

    const int x  = blockIdx.y * 8 + tx;
    const int y  = yt * 8 + ty;
    const int zq = blockIdx.x * 16 + tz * 4;

    const float fillv = fill[b];

    const double dx = (double)x, dy = (double)y, dz = (double)zq;
    double ixd = fma(c[0], dx, fma(c[1], dy, fma(c2, dz, c[3])));
    double iyd = fma(c[4], dx, fma(c[5], dy, fma(c6, dz, c[7])));
    double izd = fma(c[8], dx, fma(c[9], dy, fma(c10, dz, c[11])));

    // exact per-k validity prescan (sequential stepping, identical values to
    // the main loop, so no boundary-ulp disagreement)
    bool anyv = false;
    {
        double ax = ixd, ay = iyd, az = izd;
        #pragma unroll
        for (int k = 0; k < 4; k++) {
            anyv = anyv || ((ax >= 0.0) && (ax <= 159.0) && (ay >= 0.0) &&
                            (ay <= 159.0) && (az >= 0.0) && (az <= 159.0));
            ax += c2; ay += c6; az += c10;
        }
    }

    const float* base = img + (size_t)b * (HH * WW * DD);
    vfloat4 r;

    if (__any(anyv)) {
        #pragma unroll
        for (int k = 0; k < 4; k++) {
            const bool valid = (ixd >= 0.0) && (ixd <= 159.0) && (iyd >= 0.0) &&
                               (iyd <= 159.0) && (izd >= 0.0) && (izd <= 159.0);
            double flx = floor(ixd), fly = floor(iyd), flz = floor(izd);
            int x0 = (int)flx, y0 = (int)fly, z0 = (int)flz;
            // clamp for address safety; no-op for valid lanes
            x0 = min(max(x0, 0), 159);
            y0 = min(max(y0, 0), 159);
            z0 = min(max(z0, 0), 159);
            float fx = (float)(ixd - flx), fy = (float)(iyd - fly), fz = (float)(izd - flz);
            int x1 = min(x0 + 1, 159), y1 = min(y0 + 1, 159), z1 = min(z0 + 1, 159);
            // img[b, h=yi, w=xi, d=zi]
            const int o00 = (y0 * WW + x0) * DD;   // (y0, x0)
            const int o01 = (y0 * WW + x1) * DD;   // (y0, x1)
            const int o10 = (y1 * WW + x0) * DD;   // (y1, x0)
            const int o11 = (y1 * WW + x1) * DD;   // (y1, x1)
            float v000 = base[o00 + z0], v001 = base[o00 + z1];
            float v010 = base[o10 + z0], v011 = base[o10 + z1];
            float v100 = base[o01 + z0], v101 = base[o01 + z1];
            float v110 = base[o11 + z0], v111 = base[o11 + z1];
            float wx0 = 1.0f - fx, wx1 = fx;
            float wy0 = 1.0f - fy, wy1 = fy;
            float wz0 = 1.0f - fz, wz1 = fz;
            // accumulate in the reference's (ox, oy, oz) loop order
            float acc;
            acc  = ((wx0 * wy0) * wz0) * v000;
            acc += ((wx0 * wy0) * wz1) * v001;
            acc += ((wx0 * wy1) * wz0) * v010;
            acc += ((wx0 * wy1) * wz1) * v011;
            acc += ((wx1 * wy0) * wz0) * v100;
            acc += ((wx1 * wy0) * wz1) * v101;
            acc += ((wx1 * wy1) * wz0) * v110;
            acc += ((wx1 * wy1) * wz1) * v111;
            r[k] = valid ? acc : fillv;
            ixd += c2; iyd += c6; izd += c10;
        }
    } else {
        r[0] = fillv; r[1] = fillv; r[2] = fillv; r[3] = fillv;
    }

    vfloat4* outp = (vfloat4*)(out + (size_t)((b * HH + y) * WW + x) * DD + zq);
    __builtin_nontemporal_store(r, outp);
}

extern "C" void kernel_launch(void* const* d_in, const int* in_sizes, int n_in,
                              void* d_out, int out_size, void* d_ws, size_t ws_size,
                              hipStream_t stream) {
    const float* img = (const float*)d_in[0];
    const float* transfos = (const float*)d_in[1];
    float* out = (float*)d_out;
    float* partial = (float*)d_ws;                      // 1024 floats
    double* cst = (double*)((char*)d_ws + 4096);        // 48 doubles
    float* fill = (float*)((char*)d_ws + 8192);         // 4 floats

    min_cst_kernel<<<dim3(K1B, BB), 256, 0, stream>>>((const float4*)img, transfos,
                                                      partial, cst);
    fin_min_kernel<<<dim3(1), 256, 0, stream>>>(partial, fill);
    fill_kernel<<<dim3(512, BB), 256, 0, stream>>>(fill, out);
    st3d_kernel<<<dim3(DD / 16, WW / 8, (HH / 8) * BB), 256, 0, stream>>>(img, cst,
                                                                          fill, out);
}

// Round 4
// 135.308 us; speedup vs baseline: 1.0922x; 1.0661x over previous
//
#include <hip/hip_runtime.h>

#define HH 160
#define WW 160
#define DD 160
#define BB 4
#define NPB (HH * WW * DD / 4)   // 1,024,000 float4 per batch
#define K1B 256                   // min-pass blocks per batch
#define NTZ 10                    // z tiles (16 z each)
#define NTX 20                    // x tiles (8 x each)
#define NTY 20                    // y tiles (8 y each)
#define NTILES (BB * NTY * NTX * NTZ)   // 16000
#define JCAP (NTILES * 4)               // 64000 wave-jobs max (4 per tile)
#define GBLK 2048                        // gather kernel blocks

typedef float vfloat4 __attribute__((ext_vector_type(4)));

// ---- kernel 1: per-batch block-partial min (NO atomics) + affine constants ----
__global__ __launch_bounds__(256) void min_cst_kernel(const float4* __restrict__ img4,
                                                      const float* __restrict__ transfos,
                                                      float* __restrict__ partial,
                                                      double* __restrict__ cst) {
    const int b = blockIdx.y;
    const size_t base = (size_t)b * NPB;
    const int t0 = blockIdx.x * 256 + threadIdx.x;   // < 65536
    const int S = K1B * 256;                          // 65536

    float m = 3.4e38f;
    #pragma unroll
    for (int r = 0; r < 4; r++) {
        const int i0 = t0 + 4 * r * S;
        float4 v0 = img4[base + i0];
        float4 v1 = img4[base + i0 + S];
        float4 v2 = img4[base + i0 + 2 * S];
        float4 v3 = make_float4(3.4e38f, 3.4e38f, 3.4e38f, 3.4e38f);
        if (i0 + 3 * S < NPB) v3 = img4[base + i0 + 3 * S];   // only r==3 can fail
        m = fminf(m, fminf(fminf(v0.x, v0.y), fminf(v0.z, v0.w)));
        m = fminf(m, fminf(fminf(v1.x, v1.y), fminf(v1.z, v1.w)));
        m = fminf(m, fminf(fminf(v2.x, v2.y), fminf(v2.z, v2.w)));
        m = fminf(m, fminf(fminf(v3.x, v3.y), fminf(v3.z, v3.w)));
    }

    #pragma unroll
    for (int o = 32; o >= 1; o >>= 1) m = fminf(m, __shfl_down(m, o));
    __shared__ float s[4];
    const int lane = threadIdx.x & 63, wid = threadIdx.x >> 6;
    if (lane == 0) s[wid] = m;
    __syncthreads();
    if (threadIdx.x == 0) {
        partial[b * K1B + blockIdx.x] =
            fminf(fminf(s[0], s[1]), fminf(s[2], s[3]));
    }

    if (blockIdx.x == 0 && blockIdx.y == 0 && threadIdx.x < BB) {
        const int bb = threadIdx.x;
        const float* q = transfos + bb * 7;
        double x = q[0], y = q[1], z = q[2], w = q[3];
        double tx = 2.0 * x, ty = 2.0 * y, tz = 2.0 * z;
        double twx = tx * w, twy = ty * w, twz = tz * w;
        double txx = tx * x, txy = ty * x, txz = tz * x;
        double tyy = ty * y, tyz = tz * y, tzz = tz * z;
        double R[3][3] = {
            {1.0 - (tyy + tzz), txy - twz,         txz + twy},
            {txy + twz,         1.0 - (txx + tzz), tyz - twx},
            {txz - twy,         tyz + twx,         1.0 - (txx + tyy)}
        };
        double t[3] = {(double)q[4], (double)q[5], (double)q[6]};
        for (int r = 0; r < 3; r++) {
            cst[bb * 12 + r * 4 + 0] = R[r][0];
            cst[bb * 12 + r * 4 + 1] = R[r][1];
            cst[bb * 12 + r * 4 + 2] = R[r][2];
            cst[bb * 12 + r * 4 + 3] = 79.5 * (t[r] - R[r][0] - R[r][1] - R[r][2] + 1.0);
        }
    }
}

// ---- kernel 1b: final per-batch min + zero the job counter ----
__global__ __launch_bounds__(256) void fin_min_kernel(const float* __restrict__ partial,
                                                      float* __restrict__ fill,
                                                      int* __restrict__ counter) {
    if (threadIdx.x == 0) *counter = 0;
    const int wid = threadIdx.x >> 6, lane = threadIdx.x & 63;
    const float* p = partial + wid * K1B;
    float m = fminf(fminf(p[lane], p[lane + 64]), fminf(p[lane + 128], p[lane + 192]));
    #pragma unroll
    for (int o = 32; o >= 1; o >>= 1) m = fminf(m, __shfl_down(m, o));
    if (lane == 0) fill[wid] = m;
}

// ---- device helper: conservative tile interval test (block-uniform) ----
__device__ __forceinline__ bool tile_may_be_valid(const double* c, int xt, int yt, int zt) {
    const double X0 = (double)(xt * 8), X1 = X0 + 7.0;
    const double Y0 = (double)(yt * 8), Y1 = Y0 + 7.0;
    const double Z0 = (double)(zt * 16), Z1 = Z0 + 15.0;
    double lo, hi, t;

    lo = c[3]; hi = c[3];
    t = c[0]; if (t >= 0.0) { lo += t * X0; hi += t * X1; } else { lo += t * X1; hi += t * X0; }
    t = c[1]; if (t >= 0.0) { lo += t * Y0; hi += t * Y1; } else { lo += t * Y1; hi += t * Y0; }
    t = c[2]; if (t >= 0.0) { lo += t * Z0; hi += t * Z1; } else { lo += t * Z1; hi += t * Z0; }
    if (hi < -1e-3 || lo > 159.001) return false;

    lo = c[7]; hi = c[7];
    t = c[4]; if (t >= 0.0) { lo += t * X0; hi += t * X1; } else { lo += t * X1; hi += t * X0; }
    t = c[5]; if (t >= 0.0) { lo += t * Y0; hi += t * Y1; } else { lo += t * Y1; hi += t * Y0; }
    t = c[6]; if (t >= 0.0) { lo += t * Z0; hi += t * Z1; } else { lo += t * Z1; hi += t * Z0; }
    if (hi < -1e-3 || lo > 159.001) return false;

    lo = c[11]; hi = c[11];
    t = c[8]; if (t >= 0.0) { lo += t * X0; hi += t * X1; } else { lo += t * X1; hi += t * X0; }
    t = c[9]; if (t >= 0.0) { lo += t * Y0; hi += t * Y1; } else { lo += t * Y1; hi += t * Y0; }
    t = c[10]; if (t >= 0.0) { lo += t * Z0; hi += t * Z1; } else { lo += t * Z1; hi += t * Z0; }
    if (hi < -1e-3 || lo > 159.001) return false;
    return true;
}

// ---- kernel 2: fill non-survivor tiles + append survivor wave-jobs ----
// grid (NTZ, NTX, NTY*BB) x 256. Survivor tiles: thread 0 appends 4 wave-jobs
// (tileId*4 + pair) to the list; their voxels are written entirely by the
// gather kernel. Non-survivors: write fillv (full 64B-line stores).
__global__ __launch_bounds__(256) void fill_cls_kernel(const double* __restrict__ cst,
                                                       const float* __restrict__ fill,
                                                       float* __restrict__ out,
                                                       int* __restrict__ counter,
                                                       int* __restrict__ list) {
    const int bzc = blockIdx.z;
    const int b = bzc / NTY;
    const int yt = bzc - b * NTY;
    const double* c = cst + b * 12;

    if (tile_may_be_valid(c, blockIdx.y, yt, blockIdx.x)) {
        if (threadIdx.x == 0) {
            const int t = ((b * NTY + yt) * NTX + blockIdx.y) * NTZ + blockIdx.x;
            const int idx = atomicAdd(counter, 4);
            list[idx + 0] = t * 4 + 0;
            list[idx + 1] = t * 4 + 1;
            list[idx + 2] = t * 4 + 2;
            list[idx + 3] = t * 4 + 3;
        }
        return;
    }

    const float fv = fill[b];
    vfloat4 v; v[0] = fv; v[1] = fv; v[2] = fv; v[3] = fv;
    const int tz = threadIdx.x & 3;
    const int tx = (threadIdx.x >> 2) & 7;
    const int ty = threadIdx.x >> 5;
    const int x = blockIdx.y * 8 + tx;
    const int y = yt * 8 + ty;
    const int zq = blockIdx.x * 16 + tz * 4;
    __builtin_nontemporal_store(v, (vfloat4*)(out + (size_t)((b * HH + y) * WW + x) * DD + zq));
}

// ---- kernel 3: gather over the compacted job list, one wave per job ----
// Job = tileId*4 + pair; wave covers the 2y x 8x x 16z brick (lane mapping
// identical to the round-3 survivor path: tz=lane&3, tx=(lane>>2)&7,
// tyl=lane>>5, y = yt*8 + pair*2 + tyl). Jobs are consumed round-robin so
// gather waves spread evenly across CUs regardless of where the valid slab
// sits in the output volume. Per-voxel math verbatim (bit-identical).
__global__ __launch_bounds__(256) void gather_kernel(const float* __restrict__ img,
                                                     const double* __restrict__ cst,
                                                     const float* __restrict__ fill,
                                                     float* __restrict__ out,
                                                     const int* __restrict__ counter,
                                                     const int* __restrict__ list) {
    const int cnt = *counter;
    const int wid = threadIdx.x >> 6;
    const int lane = threadIdx.x & 63;
    const int tz = lane & 3;
    const int tx = (lane >> 2) & 7;
    const int tyl = lane >> 5;
    const int nslots = gridDim.x * 4;

    for (int j = blockIdx.x * 4 + wid; j < cnt; j += nslots) {
        const int job = list[j];
        const int t = job >> 2, pair = job & 3;
        int zt = t % NTZ;
        int r0i = t / NTZ;
        int xt = r0i % NTX; r0i /= NTX;
        int yt = r0i % NTY;
        const int b = r0i / NTY;

        const int x = xt * 8 + tx;
        const int y = yt * 8 + pair * 2 + tyl;
        const int zq = zt * 16 + tz * 4;

        const double* c = cst + b * 12;
        const double c2 = c[2], c6 = c[6], c10 = c[10];
        const float fillv = fill[b];

        const double dx = (double)x, dy = (double)y, dz = (double)zq;
        double ixd = fma(c[0], dx, fma(c[1], dy, fma(c2, dz, c[3])));
        double iyd = fma(c[4], dx, fma(c[5], dy, fma(c6, dz, c[7])));
        double izd = fma(c[8], dx, fma(c[9], dy, fma(c10, dz, c[11])));

        // exact per-k validity prescan (sequential stepping, identical values
        // to the main loop, so no boundary-ulp disagreement)
        bool anyv = false;
        {
            double ax = ixd, ay = iyd, az = izd;
            #pragma unroll
            for (int k = 0; k < 4; k++) {
                anyv = anyv || ((ax >= 0.0) && (ax <= 159.0) && (ay >= 0.0) &&
                                (ay <= 159.0) && (az >= 0.0) && (az <= 159.0));
                ax += c2; ay += c6; az += c10;
            }
        }

        const float* base = img + (size_t)b * (HH * WW * DD);
        vfloat4 r;

        if (__any(anyv)) {
            #pragma unroll
            for (int k = 0; k < 4; k++) {
                const bool valid = (ixd >= 0.0) && (ixd <= 159.0) && (iyd >= 0.0) &&
                                   (iyd <= 159.0) && (izd >= 0.0) && (izd <= 159.0);
                double flx = floor(ixd), fly = floor(iyd), flz = floor(izd);
                int x0 = (int)flx, y0 = (int)fly, z0 = (int)flz;
                x0 = min(max(x0, 0), 159);
                y0 = min(max(y0, 0), 159);
                z0 = min(max(z0, 0), 159);
                float fx = (float)(ixd - flx), fy = (float)(iyd - fly), fz = (float)(izd - flz);
                int x1 = min(x0 + 1, 159), y1 = min(y0 + 1, 159), z1 = min(z0 + 1, 159);
                const int o00 = (y0 * WW + x0) * DD;   // (y0, x0)
                const int o01 = (y0 * WW + x1) * DD;   // (y0, x1)
                const int o10 = (y1 * WW + x0) * DD;   // (y1, x0)
                const int o11 = (y1 * WW + x1) * DD;   // (y1, x1)
                float v000 = base[o00 + z0], v001 = base[o00 + z1];
                float v010 = base[o10 + z0], v011 = base[o10 + z1];
                float v100 = base[o01 + z0], v101 = base[o01 + z1];
                float v110 = base[o11 + z0], v111 = base[o11 + z1];
                float wx0 = 1.0f - fx, wx1 = fx;
                float wy0 = 1.0f - fy, wy1 = fy;
                float wz0 = 1.0f - fz, wz1 = fz;
                float acc;
                acc  = ((wx0 * wy0) * wz0) * v000;
                acc += ((wx0 * wy0) * wz1) * v001;
                acc += ((wx0 * wy1) * wz0) * v010;
                acc += ((wx0 * wy1) * wz1) * v011;
                acc += ((wx1 * wy0) * wz0) * v100;
                acc += ((wx1 * wy0) * wz1) * v101;
                acc += ((wx1 * wy1) * wz0) * v110;
                acc += ((wx1 * wy1) * wz1) * v111;
                r[k] = valid ? acc : fillv;
                ixd += c2; iyd += c6; izd += c10;
            }
        } else {
            r[0] = fillv; r[1] = fillv; r[2] = fillv; r[3] = fillv;
        }

        __builtin_nontemporal_store(r, (vfloat4*)(out + (size_t)((b * HH + y) * WW + x) * DD + zq));
    }
}

// ---- fallback (small workspace): round-3 fill + tile-skip gather ----
__global__ __launch_bounds__(256) void fill_kernel(const float* __restrict__ fill,
                                                   float* __restrict__ out) {
    const int b = blockIdx.y;
    const float fv = fill[b];
    vfloat4 v; v[0] = fv; v[1] = fv; v[2] = fv; v[3] = fv;
    vfloat4* o = (vfloat4*)(out + (size_t)b * (HH * WW * DD));
    const int stride = gridDim.x * 256;
    for (int i = blockIdx.x * 256 + threadIdx.x; i < NPB; i += stride)
        __builtin_nontemporal_store(v, o + i);
}

__global__ __launch_bounds__(256) void st3d_tile_kernel(const float* __restrict__ img,
                                                        const double* __restrict__ cst,
                                                        const float* __restrict__ fill,
                                                        float* __restrict__ out) {
    const int bzc = blockIdx.z;
    const int b = bzc / NTY;
    const int yt = bzc - b * NTY;
    const double* c = cst + b * 12;
    if (!tile_may_be_valid(c, blockIdx.y, yt, blockIdx.x)) return;

    const double c2 = c[2], c6 = c[6], c10 = c[10];
    const int tz = threadIdx.x & 3;
    const int tx = (threadIdx.x >> 2) & 7;
    const int ty = threadIdx.x >> 5;
    const int x = blockIdx.y * 8 + tx;
    const int y = yt * 8 + ty;
    const int zq = blockIdx.x * 16 + tz * 4;
    const float fillv = fill[b];

    const double dx = (double)x, dy = (double)y, dz = (double)zq;
    double ixd = fma(c[0], dx, fma(c[1], dy, fma(c2, dz, c[3])));
    double iyd = fma(c[4], dx, fma(c[5], dy, fma(c6, dz, c[7])));
    double izd = fma(c[8], dx, fma(c[9], dy, fma(c10, dz, c[11])));

    bool anyv = false;
    {
        double ax = ixd, ay = iyd, az = izd;
        #pragma unroll
        for (int k = 0; k < 4; k++) {
            anyv = anyv || ((ax >= 0.0) && (ax <= 159.0) && (ay >= 0.0) &&
                            (ay <= 159.0) && (az >= 0.0) && (az <= 159.0));
            ax += c2; ay += c6; az += c10;
        }
    }

    const float* base = img + (size_t)b * (HH * WW * DD);
    vfloat4 r;
    if (__any(anyv)) {
        #pragma unroll
        for (int k = 0; k < 4; k++) {
            const bool valid = (ixd >= 0.0) && (ixd <= 159.0) && (iyd >= 0.0) &&
                               (iyd <= 159.0) && (izd >= 0.0) && (izd <= 159.0);
            double flx = floor(ixd), fly = floor(iyd), flz = floor(izd);
            int x0 = (int)flx, y0 = (int)fly, z0 = (int)flz;
            x0 = min(max(x0, 0), 159);
            y0 = min(max(y0, 0), 159);
            z0 = min(max(z0, 0), 159);
            float fx = (float)(ixd - flx), fy = (float)(iyd - fly), fz = (float)(izd - flz);
            int x1 = min(x0 + 1, 159), y1 = min(y0 + 1, 159), z1 = min(z0 + 1, 159);
            const int o00 = (y0 * WW + x0) * DD;
            const int o01 = (y0 * WW + x1) * DD;
            const int o10 = (y1 * WW + x0) * DD;
            const int o11 = (y1 * WW + x1) * DD;
            float v000 = base[o00 + z0], v001 = base[o00 + z1];
            float v010 = base[o10 + z0], v011 = base[o10 + z1];
            float v100 = base[o01 + z0], v101 = base[o01 + z1];
            float v110 = base[o11 + z0], v111 = base[o11 + z1];
            float wx0 = 1.0f - fx, wx1 = fx;
            float wy0 = 1.0f - fy, wy1 = fy;
            float wz0 = 1.0f - fz, wz1 = fz;
            float acc;
            acc  = ((wx0 * wy0) * wz0) * v000;
            acc += ((wx0 * wy0) * wz1) * v001;
            acc += ((wx0 * wy1) * wz0) * v010;
            acc += ((wx0 * wy1) * wz1) * v011;
            acc += ((wx1 * wy0) * wz0) * v100;
            acc += ((wx1 * wy0) * wz1) * v101;
            acc += ((wx1 * wy1) * wz0) * v110;
            acc += ((wx1 * wy1) * wz1) * v111;
            r[k] = valid ? acc : fillv;
            ixd += c2; iyd += c6; izd += c10;
        }
    } else {
        r[0] = fillv; r[1] = fillv; r[2] = fillv; r[3] = fillv;
    }
    __builtin_nontemporal_store(r, (vfloat4*)(out + (size_t)((b * HH + y) * WW + x) * DD + zq));
}

extern "C" void kernel_launch(void* const* d_in, const int* in_sizes, int n_in,
                              void* d_out, int out_size, void* d_ws, size_t ws_size,
                              hipStream_t stream) {
    const float* img = (const float*)d_in[0];
    const float* transfos = (const float*)d_in[1];
    float* out = (float*)d_out;
    float* partial = (float*)d_ws;                      // [0, 4096): 1024 floats
    double* cst = (double*)((char*)d_ws + 4096);        // 48 doubles
    float* fill = (float*)((char*)d_ws + 8192);         // 4 floats
    int* counter = (int*)((char*)d_ws + 8448);          // 1 int
    int* list = (int*)((char*)d_ws + 8704);             // up to 64000 ints

    min_cst_kernel<<<dim3(K1B, BB), 256, 0, stream>>>((const float4*)img, transfos,
                                                      partial, cst);
    fin_min_kernel<<<dim3(1), 256, 0, stream>>>(partial, fill, counter);

    if (ws_size >= (size_t)(8704 + JCAP * 4)) {
        fill_cls_kernel<<<dim3(NTZ, NTX, NTY * BB), 256, 0, stream>>>(cst, fill, out,
                                                                      counter, list);
        gather_kernel<<<dim3(GBLK), 256, 0, stream>>>(img, cst, fill, out, counter, list);
    } else {
        fill_kernel<<<dim3(512, BB), 256, 0, stream>>>(fill, out);
        st3d_tile_kernel<<<dim3(NTZ, NTX, NTY * BB), 256, 0, stream>>>(img, cst, fill, out);
    }
}